// Round 16
// baseline (632.708 us; speedup 1.0000x reference)
//
#include <hip/hip_runtime.h>
#include <hip/hip_bf16.h>

#define HD 512      // d_model
#define NST 64      // d_state
#define NLAY 6
#define LSEQ 784
#define BB 64       // batch
#define NKA 848     // reversed+padded kernel array length (u16)
#define TOFF 800    // KA[t] = K[TOFF - t]; t in [17,800] real, else 0
#define LPADROWS 800  // padded L (25 tiles of 32); pad rows killed by zero-K
#define KSTR 850    // u16 stride between shifted K copies
#define CHK2 5      // 32-row l-tiles per conv block; 25 = 5*5
#define NCH 5       // chunks
#define UTS2 9      // UT row stride in dwords (8 j-pairs + 1 pad)
#define KQC 8       // d's per kq thread
#define KQT 98      // kq threads per (i,h)

typedef unsigned short u16;
typedef short s8v __attribute__((ext_vector_type(8)));   // 8 bf16 (4 VGPR)
typedef float f16v __attribute__((ext_vector_type(16))); // 32x32 MFMA acc
typedef u16  u4h __attribute__((ext_vector_type(4)));    // ushort4 (8B)
typedef u16  u8h __attribute__((ext_vector_type(8)));    // ushort8 (16B)

// fp32 -> bf16 bits, round-to-nearest-even
__device__ __forceinline__ unsigned f2b(float f)
{
    unsigned u = __builtin_bit_cast(unsigned, f);
    return (u + 0x7FFFu + ((u >> 16) & 1u)) >> 16;
}
__device__ __forceinline__ float b2f16(u16 v)
{
    unsigned u = ((unsigned)v) << 16;
    return __builtin_bit_cast(float, u);
}

// ---------------------------------------------------------------------------
// Fused param-compute + conv-kernel build (bf16, reversed, zero-padded).
// Block: stages lambda/dtA/2Cd for its <=4 (i,h) sets into LDS (computed
// from raw inputs — no precompute pass, no global param round-trip), then
// thread (ih, dc) computes K[d], d = 8*dc .. 8*dc+7:
//   K[d] = sum_n 2Re(Cd_n lam_n^d), anchored by exp/sincos, iterated x8.
// 1176 blocks (~4.6 waves/SIMD) + LDS-broadcast param reads -> latency
// hidden (round-15 kq_k was 2.3 waves/SIMD with 6 global loads/state).
// ---------------------------------------------------------------------------
__global__ __launch_bounds__(256)
void kq_k(const float* __restrict__ log_dt, const float* __restrict__ log_A_real,
          const float* __restrict__ A_imag, const float* __restrict__ C_re,
          const float* __restrict__ C_im, u16* __restrict__ KA)
{
    __shared__ __align__(16) float LP[4][64][8];
    const int thr = threadIdx.x;
    const int g = blockIdx.x * 256 + thr;     // grid exact: 3072*98
    const int ihbase = (blockIdx.x * 256) / KQT;

    {   // param staging: thread = (set = thr>>6, n = thr&63)
        int set = thr >> 6, n = thr & 63;
        int ihp = ihbase + set;
        if (ihp < NLAY * HD) {
            int t = ihp * 64 + n;
            float dt  = expf(log_dt[ihp]);
            float are = -expf(log_A_real[t]);
            float aim = A_imag[t];
            float dr = are * dt, di = aim * dt;
            float er = expf(dr);
            float sn, cs; __sincosf(di, &sn, &cs);
            float lr = er * cs, li = er * sn;          // lambda
            float e1r = lr - 1.0f, e1i = li;
            float den = are * are + aim * aim;
            float qr = (e1r * are + e1i * aim) / den;
            float qi = (e1i * are - e1r * aim) / den;
            float crv = C_re[t], civ = C_im[t];
            LP[set][n][0] = lr; LP[set][n][1] = li;
            LP[set][n][2] = dr; LP[set][n][3] = di;
            LP[set][n][4] = 2.0f * (crv * qr - civ * qi);
            LP[set][n][5] = 2.0f * (crv * qi + civ * qr);
            LP[set][n][6] = 0.f; LP[set][n][7] = 0.f;
        }
    }
    __syncthreads();

    const int ih = g / KQT;
    const int dc = g % KQT;
    const int set = ih - ihbase;              // 0..3
    const int d0 = KQC * dc;
    const float fd0 = (float)d0;

    float acc[KQC];
#pragma unroll
    for (int k = 0; k < KQC; k++) acc[k] = 0.f;
#pragma unroll 2
    for (int n = 0; n < 64; n++) {
        float4 p0 = *(const float4*)&LP[set][n][0];   // lr li dr di (broadcast)
        float4 p1 = *(const float4*)&LP[set][n][4];   // cr ci - -
        float e = __expf(p0.z * fd0);
        float sn, cs; __sincosf(p0.w * fd0, &sn, &cs);
        float pr = e * cs, pi = e * sn;               // lam^d0
#pragma unroll
        for (int k = 0; k < KQC; k++) {
            acc[k] = fmaf(p1.x, pr, fmaf(-p1.y, pi, acc[k]));
            float nr = pr * p0.x - pi * p0.y;
            pi = fmaf(pr, p0.y, pi * p0.x);
            pr = nr;
        }
    }
    u16* kap = KA + (size_t)ih * NKA;
#pragma unroll
    for (int k = 0; k < KQC; k++)
        kap[TOFF - (d0 + k)] = (u16)f2b(acc[k]);
    if (dc == 0)       for (int z = TOFF + 1; z < NKA; z++) kap[z] = 0;
    if (dc == KQT - 1) for (int z = 0; z < TOFF - 783; z++) kap[z] = 0;
}

// ---------------------------------------------------------------------------
// Transpose x[b][l] -> xT[l][b] (200 KB, L2-resident; cost ~2 us)
// ---------------------------------------------------------------------------
__global__ void xt_k(const float* __restrict__ x, float* __restrict__ xT)
{
    int t = blockIdx.x * 256 + threadIdx.x;   // < 784*64
    int l = t >> 6, b = t & 63;
    xT[t] = x[b * LSEQ + l];
}

// ---------------------------------------------------------------------------
// Encoder: thread = (l, h, b-oct). Reads 8 fp32 from xT (coalesced),
// writes 8 packed bf16 (uint4, 16B) -> 1KB/wave contiguous stores.
// ---------------------------------------------------------------------------
__global__ void encoder_k(const float* __restrict__ xT, const float* __restrict__ ew,
                          const float* __restrict__ eb, u16* __restrict__ Vb)
{
    int g = blockIdx.x * 256 + threadIdx.x;   // < 784*512*8
    int bo = g & 7;
    int h  = (g >> 3) & 511;
    int l  = g >> 12;
    const float4* xp = (const float4*)&xT[l * BB + 8 * bo];
    float4 a0 = xp[0], a1 = xp[1];
    float w = ew[h], bb = eb[h];
    unsigned p0 = f2b(fmaf(a0.x, w, bb)) | (f2b(fmaf(a0.y, w, bb)) << 16);
    unsigned p1 = f2b(fmaf(a0.z, w, bb)) | (f2b(fmaf(a0.w, w, bb)) << 16);
    unsigned p2 = f2b(fmaf(a1.x, w, bb)) | (f2b(fmaf(a1.y, w, bb)) << 16);
    unsigned p3 = f2b(fmaf(a1.z, w, bb)) | (f2b(fmaf(a1.w, w, bb)) << 16);
    *(uint4*)&Vb[((size_t)l * HD + h) * BB + 8 * bo] = (uint4){p0, p1, p2, p3};
}

// ---------------------------------------------------------------------------
// MFMA causal-Toeplitz conv + residual via 32x32x16 bf16 MFMA.
// (unchanged from round 14/15 — see comments there)
// ---------------------------------------------------------------------------
__global__ __launch_bounds__(128, 4)
void conv_k(const u16* __restrict__ Vb, u16* __restrict__ V2,
            const u16* __restrict__ KA, const float* __restrict__ Dvec)
{
    __shared__ __align__(16) u16 KR[6816];           // 8 shifted copies
    __shared__ __align__(16) unsigned UT[2][64 * UTS2];

    const int thr = threadIdx.x;
    const int h   = blockIdx.x & 511;
    const int c   = blockIdx.x >> 9;         // 0..4
    const int w   = thr >> 6;                // b-half (n-tile)
    const int lane = thr & 63;
    const int n2 = lane & 31;
    const int qp = lane >> 5;
    const int JTN = 10 * c + 10;

    const u16* kap = KA + (size_t)h * NKA;
    {
        int s = thr & 7, ch = thr >> 3;      // 16 chunks x 53 (covers 848)
        int i0 = ch * 53;
        int i1 = (i0 + 53 < NKA) ? (i0 + 53) : NKA;
        u16* kr = KR + KSTR * s + ((8 - s) & 7);
        for (int i = i0; i < i1; i++) kr[i] = kap[i];
    }

    const int jj = thr >> 4;
    const int bq = thr & 15;
    {   // stage tile jt=0 (j rows 0..15)
        const u16* p = &Vb[((size_t)(2 * jj) * HD + h) * BB + 4 * bq];
        u4h r0 = *(const u4h*)p;
        u4h r1 = *(const u4h*)(p + (size_t)HD * BB);
        unsigned* up = &UT[0][0];
#pragma unroll
        for (int i = 0; i < 4; i++)
            up[(4 * bq + i) * UTS2 + jj] = (unsigned)r0[i] | ((unsigned)r1[i] << 16);
    }
    __syncthreads();

    f16v acc[CHK2];
#pragma unroll
    for (int i = 0; i < CHK2; i++)
#pragma unroll
        for (int r = 0; r < 16; r++) acc[i][r] = 0.f;

    const float dcoef = 1.0f + Dvec[h];

    const int s = lane & 7;
    const u16* krb = KR + KSTR * s + ((8 - s) & 7)
                     + (TOFF - 160 * c) + 8 * qp - n2;
    const unsigned* bb0 = &UT[0][(32 * w + n2) * UTS2 + 4 * qp];
    const unsigned* bb1 = &UT[1][(32 * w + n2) * UTS2 + 4 * qp];

    for (int jt = 0; jt < JTN; ++jt) {
        u4h r0, r1;
        const bool more = (jt + 1) < JTN;
        if (more) {
            int j = 16 * (jt + 1) + 2 * jj;
            const u16* p = &Vb[((size_t)j * HD + h) * BB + 4 * bq];
            r0 = *(const u4h*)p;
            r1 = *(const u4h*)(p + (size_t)HD * BB);
        }
        const unsigned* bb = (jt & 1) ? bb1 : bb0;
        union { unsigned u[4]; s8v v; } bu;
        bu.u[0] = bb[0]; bu.u[1] = bb[1]; bu.u[2] = bb[2]; bu.u[3] = bb[3];

        const u16* ap0 = krb + 16 * jt;
#pragma unroll
        for (int lt = 0; lt < CHK2; ++lt) {
            if (jt > 10 * c + 2 * lt + 1) continue;   // tile done (uniform)
            s8v av = *(const s8v*)__builtin_assume_aligned(ap0 - 32 * lt, 16);
            acc[lt] = __builtin_amdgcn_mfma_f32_32x32x16_bf16(av, bu.v, acc[lt], 0, 0, 0);
        }
        if (more) {
            unsigned* up = &UT[(jt & 1) ^ 1][0];
#pragma unroll
            for (int i = 0; i < 4; i++)
                up[(4 * bq + i) * UTS2 + jj] = (unsigned)r0[i] | ((unsigned)r1[i] << 16);
        }
        __syncthreads();
    }

    // epilogue: V2 = bf16(y + (1+D)*u)
#pragma unroll
    for (int lt = 0; lt < CHK2; ++lt) {
        const int l0 = 32 * (5 * c + lt) + 4 * qp;
#pragma unroll
        for (int r = 0; r < 16; ++r) {
            int l = l0 + (r & 3) + 8 * (r >> 2);
            size_t a = ((size_t)l * HD + h) * BB + 32 * w + n2;
            V2[a] = (u16)f2b(fmaf(dcoef, b2f16(Vb[a]), acc[lt][r]));
        }
    }
}

// ---------------------------------------------------------------------------
// LayerNorm over h in [l][h][b]; bf16 in/out, fp32 math, u8h (16B) I/O.
// Block = one l, 512 thr: thread (bo = b-oct 0..7, hg = h-group-of-8 0..63).
// ---------------------------------------------------------------------------
__global__ __launch_bounds__(512)
void lnT_k(const u16* __restrict__ src, u16* __restrict__ dst,
           const float* __restrict__ gp, const float* __restrict__ bp)
{
    __shared__ float redS[64][65], redQ[64][65];
    __shared__ float mus[64], rss[64];
    __shared__ float gs[512], bs[512];
    const int thr = threadIdx.x;
    const int bo = thr & 7;           // b = 8*bo + i
    const int hg = thr >> 3;          // h = 8*hg + k
    const size_t l = blockIdx.x;
    gs[thr] = gp[thr]; bs[thr] = bp[thr];

    const u16* sp = &src[(l * HD + hg * 8) * BB + 8 * bo];
    float v[64];                       // v[k*8+i]
    float s[8] = {0, 0, 0, 0, 0, 0, 0, 0};
    float q[8] = {0, 0, 0, 0, 0, 0, 0, 0};
#pragma unroll
    for (int k = 0; k < 8; k++) {
        u8h r = *(const u8h*)(sp + (size_t)k * BB);
#pragma unroll
        for (int i = 0; i < 8; i++) {
            float x = b2f16(r[i]);
            v[k * 8 + i] = x;
            s[i] += x;
            q[i] = fmaf(x, x, q[i]);
        }
    }
#pragma unroll
    for (int i = 0; i < 8; i++) { redS[hg][8 * bo + i] = s[i]; redQ[hg][8 * bo + i] = q[i]; }
    __syncthreads();
    if (thr < 64) {
        float ts = 0.f, tq = 0.f;
#pragma unroll
        for (int g = 0; g < 64; g++) { ts += redS[g][thr]; tq += redQ[g][thr]; }
        float mu = ts * (1.0f / HD);
        mus[thr] = mu;
        rss[thr] = rsqrtf(tq * (1.0f / HD) - mu * mu + 1e-5f);
    }
    __syncthreads();
    float mu[8], rs[8];
#pragma unroll
    for (int i = 0; i < 8; i++) { mu[i] = mus[8 * bo + i]; rs[i] = rss[8 * bo + i]; }
    u16* dp = &dst[(l * HD + hg * 8) * BB + 8 * bo];
#pragma unroll
    for (int k = 0; k < 8; k++) {
        float g = gs[hg * 8 + k], bb = bs[hg * 8 + k];
        u8h w;
#pragma unroll
        for (int i = 0; i < 8; i++)
            w[i] = (u16)f2b(fmaf((v[k * 8 + i] - mu[i]) * rs[i], g, bb));
        *(u8h*)(dp + (size_t)k * BB) = w;
    }
}

// ---------------------------------------------------------------------------
// Mean-pool over l from bf16 Vb: PO[h*64+b] = mean_l Vb[l][h][b].
// ---------------------------------------------------------------------------
__global__ void pool_k(const u16* __restrict__ Vb, float* __restrict__ PO)
{
    __shared__ float red[4][64];
    int h = blockIdx.x;
    int b = threadIdx.x & 63;
    int lg = threadIdx.x >> 6;               // 0..3
    const u16* p = &Vb[(size_t)h * BB + b];
    float s = 0.f;
    for (int l = lg; l < LSEQ; l += 4) s += b2f16(p[(size_t)l * HD * BB]);
    red[lg][b] = s;
    __syncthreads();
    if (threadIdx.x < 64) {
        float t = red[0][b] + red[1][b] + red[2][b] + red[3][b];
        PO[h * BB + b] = t * (1.0f / LSEQ);
    }
}

// ---------------------------------------------------------------------------
// Decoder: out[b,c] = PO[:,b] . dec_w[:,c] + dec_b[c]
// ---------------------------------------------------------------------------
__global__ void dec_k(const float* __restrict__ PO, const float* __restrict__ w,
                      const float* __restrict__ bias, float* __restrict__ out)
{
    int t = blockIdx.x * 256 + threadIdx.x;
    if (t >= BB * 10) return;
    int cc = t % 10, b = t / 10;
    float acc = bias[cc];
    for (int hh = 0; hh < HD; hh++)
        acc = fmaf(PO[hh * BB + b], w[hh * 10 + cc], acc);
    out[t] = acc;
}

// ---------------------------------------------------------------------------
extern "C" void kernel_launch(void* const* d_in, const int* in_sizes, int n_in,
                              void* d_out, int out_size, void* d_ws, size_t ws_size,
                              hipStream_t stream)
{
    const float* x   = (const float*)d_in[0];
    const float* ew  = (const float*)d_in[1];
    const float* eb  = (const float*)d_in[2];
    const float* ldt = (const float*)d_in[3];
    const float* lar = (const float*)d_in[4];
    const float* aim = (const float*)d_in[5];
    const float* cre = (const float*)d_in[6];
    const float* cim = (const float*)d_in[7];
    const float* Dp  = (const float*)d_in[8];
    const float* lng = (const float*)d_in[9];
    const float* lnb = (const float*)d_in[10];
    const float* fng = (const float*)d_in[11];
    const float* fnb = (const float*)d_in[12];
    const float* dw  = (const float*)d_in[13];
    const float* db  = (const float*)d_in[14];
    float* out = (float*)d_out;

    const size_t SZ  = (size_t)BB * LSEQ * HD;       // 25,690,112 elems
    const size_t SZB = (size_t)BB * LPADROWS * HD;   // 26,214,400 u16 slots
    u16*   Vb  = (u16*)d_ws;                // bf16 residual stream [l][h][b]
    u16*   V2  = Vb + SZB;                  // bf16 pre-LN buffer (w/ slack)
    u16*   KA  = V2 + SZB;                  // 6*512*848 u16
    float* PO  = (float*)(KA + (size_t)NLAY * HD * NKA);
    float* xT  = PO + BB * HD;              // 784*64 fp32
    // total ~111 MB

    kq_k<<<(NLAY * HD * KQT) / 256, 256, 0, stream>>>(
        ldt, lar, aim, cre, cim, KA);
    xt_k<<<(LSEQ * BB) / 256, 256, 0, stream>>>(x, xT);
    encoder_k<<<(LSEQ * HD * 8) / 256, 256, 0, stream>>>(xT, ew, eb, Vb);

    for (int i = 0; i < NLAY; i++) {
        conv_k<<<512 * NCH, 128, 0, stream>>>(
            Vb, V2, KA + (size_t)i * HD * NKA, Dp + i * HD);
        lnT_k<<<LSEQ, 512, 0, stream>>>(V2, Vb, lng + i * HD, lnb + i * HD);
    }
    lnT_k<<<LSEQ, 512, 0, stream>>>(Vb, Vb, fng, fnb);  // final LN in place
    pool_k<<<HD, 256, 0, stream>>>(Vb, PO);
    dec_k<<<(BB * 10 + 255) / 256, 256, 0, stream>>>(PO, dw, db, out);
}